// Round 6
// baseline (280.101 us; speedup 1.0000x reference)
//
#include <hip/hip_runtime.h>
#include <hip/hip_bf16.h>
#include <math.h>

#define N_NODES 50000
#define NEG_SLOPE 0.2f
#define EPS_DEN 1e-16f

#define NBUCK 196          // ceil(N_NODES / 256)
#define NBLK  512          // edge-pass blocks

typedef float f4v __attribute__((ext_vector_type(4)));

// ---------------- alpha (prep folded in): asrc/adst[n,h] = x[n,:] . Wa[:,h] ----------------
// Wa[i][h] = sum_o W[i,h,o]*a[h,o], computed per-block into LDS (cheap, W is L2-hot).
__global__ void __launch_bounds__(256) alpha_k(
    const float* __restrict__ x, const float* __restrict__ W,
    const float* __restrict__ aS, const float* __restrict__ aD,
    float* __restrict__ asrc, float* __restrict__ adst, int N)
{
    __shared__ float Wl[512];   // [i*8 + side*4 + h]
    int tid = threadIdx.x;
    #pragma unroll
    for (int t = tid; t < 512; t += 256) {
        int i = t >> 3, r = t & 7;
        int h = r & 3, side = r >> 2;
        const float* av = (side ? aD : aS) + h * 64;
        const float* wr = W + (size_t)i * 256 + h * 64;
        float acc = 0.f;
        #pragma unroll 8
        for (int o = 0; o < 64; ++o) acc = fmaf(wr[o], av[o], acc);
        Wl[t] = acc;
    }
    __syncthreads();

    int node = blockIdx.x * 64 + (tid >> 2);
    int q = tid & 3;
    if (node >= N) return;

    float pS[4] = {0.f, 0.f, 0.f, 0.f};
    float pD[4] = {0.f, 0.f, 0.f, 0.f};
    const float* xp = x + (size_t)node * 64 + q * 16;
    #pragma unroll
    for (int j = 0; j < 4; ++j) {
        float4 xv = *(const float4*)(xp + j * 4);
        float xr[4] = {xv.x, xv.y, xv.z, xv.w};
        #pragma unroll
        for (int u = 0; u < 4; ++u) {
            int i = q * 16 + j * 4 + u;
            float4 wS = *(const float4*)(Wl + i * 8);
            float4 wD = *(const float4*)(Wl + i * 8 + 4);
            pS[0] = fmaf(xr[u], wS.x, pS[0]); pS[1] = fmaf(xr[u], wS.y, pS[1]);
            pS[2] = fmaf(xr[u], wS.z, pS[2]); pS[3] = fmaf(xr[u], wS.w, pS[3]);
            pD[0] = fmaf(xr[u], wD.x, pD[0]); pD[1] = fmaf(xr[u], wD.y, pD[1]);
            pD[2] = fmaf(xr[u], wD.z, pD[2]); pD[3] = fmaf(xr[u], wD.w, pD[3]);
        }
    }
    #pragma unroll
    for (int off = 1; off <= 2; off <<= 1) {
        #pragma unroll
        for (int h = 0; h < 4; ++h) {
            pS[h] += __shfl_xor(pS[h], off);
            pD[h] += __shfl_xor(pD[h], off);
        }
    }
    if (q == 0) {
        *(float4*)(asrc + 4 * (size_t)node) = make_float4(pS[0], pS[1], pS[2], pS[3]);
        *(float4*)(adst + 4 * (size_t)node) = make_float4(pD[0], pD[1], pD[2], pD[3]);
    }
}

// ---------------- CSR build ----------------
__global__ void zero_k(int* __restrict__ p, int n) {
    int i = blockIdx.x * blockDim.x + threadIdx.x;
    if (i < n) p[i] = 0;
}

__global__ void __launch_bounds__(256) hist_bucket_k(
    const int* __restrict__ ei, int* __restrict__ cnt, int* __restrict__ bh, int E)
{
    __shared__ int lh[NBUCK];
    int tid = threadIdx.x;
    for (int b = tid; b < NBUCK; b += 256) lh[b] = 0;
    __syncthreads();

    const int ch = (E + NBLK - 1) / NBLK;
    const int e0 = blockIdx.x * ch;
    const int e1 = min(e0 + ch, E);
    for (int e = e0 + tid; e < e1; e += 256) {
        int d = ei[E + e];
        atomicAdd(&cnt[d], 1);
        atomicAdd(&lh[d >> 8], 1);
    }
    __syncthreads();
    for (int b = tid; b < NBUCK; b += 256)
        bh[(size_t)b * NBLK + blockIdx.x] = lh[b];
}

__global__ void __launch_bounds__(1024) scan1_k(
    const int* __restrict__ cnt, int* __restrict__ excl, int* __restrict__ bsum, int n)
{
    __shared__ int sd[1024];
    int tid = threadIdx.x;
    int i = blockIdx.x * 1024 + tid;
    int v = (i < n) ? cnt[i] : 0;
    sd[tid] = v;
    __syncthreads();
    for (int off = 1; off < 1024; off <<= 1) {
        int t = (tid >= off) ? sd[tid - off] : 0;
        __syncthreads();
        sd[tid] += t;
        __syncthreads();
    }
    if (i < n) excl[i] = sd[tid] - v;
    if (tid == 1023) bsum[blockIdx.x] = sd[1023];
}

__global__ void scan2_k(int* __restrict__ bsum, int nb) {
    if (threadIdx.x == 0 && blockIdx.x == 0) {
        int acc = 0;
        for (int i = 0; i < nb; ++i) { int t = bsum[i]; bsum[i] = acc; acc += t; }
    }
}

__global__ void scan3_k(const int* __restrict__ excl, const int* __restrict__ bsum,
                        int* __restrict__ row, int n, int E)
{
    int i = blockIdx.x * blockDim.x + threadIdx.x;
    if (i < n) row[i] = excl[i] + bsum[i >> 10];
    if (i == n) row[n] = E;
}

__global__ void __launch_bounds__(64) bscan_k(
    const int* __restrict__ bh, const int* __restrict__ row,
    int* __restrict__ boff)
{
    const int b = blockIdx.x;
    const int lane = threadIdx.x;
    int v[8];
    int base = b * NBLK;
    #pragma unroll
    for (int u = 0; u < 8; ++u) v[u] = bh[base + lane * 8 + u];
    int t = 0;
    #pragma unroll
    for (int u = 0; u < 8; ++u) t += v[u];
    int run = t;
    #pragma unroll
    for (int off = 1; off < 64; off <<= 1) {
        int u = __shfl_up(run, off);
        if (lane >= off) run += u;
    }
    int lane_base = row[b << 8] + run - t;
    #pragma unroll
    for (int u = 0; u < 8; ++u) {
        boff[base + lane * 8 + u] = lane_base;
        lane_base += v[u];
    }
}

__global__ void __launch_bounds__(256) bplace_k(
    const int* __restrict__ ei, const int* __restrict__ boff,
    unsigned int* __restrict__ stage, int E)
{
    __shared__ int cur[NBUCK];
    int tid = threadIdx.x;
    for (int b = tid; b < NBUCK; b += 256)
        cur[b] = boff[(size_t)b * NBLK + blockIdx.x];
    __syncthreads();

    const int ch = (E + NBLK - 1) / NBLK;
    const int e0 = blockIdx.x * ch;
    const int e1 = min(e0 + ch, E);
    for (int e = e0 + tid; e < e1; e += 256) {
        int s = ei[e];
        int d = ei[E + e];
        int pos = atomicAdd(&cur[d >> 8], 1);
        stage[pos] = (unsigned int)s | ((unsigned int)(d & 255) << 16);
    }
}

__global__ void __launch_bounds__(256) bscatter_k(
    const unsigned int* __restrict__ stage, const int* __restrict__ row,
    int* __restrict__ psrc, int N)
{
    __shared__ int cur[256];
    const int b = blockIdx.x;
    const int tid = threadIdx.x;
    const int nb0 = b << 8;
    int node = nb0 + tid;
    cur[tid] = (node < N) ? row[node] : 0;
    __syncthreads();

    const int es = row[nb0];
    const int ee = row[min(nb0 + 256, N)];
    for (int idx = es + tid; idx < ee; idx += 256) {
        unsigned int v = stage[idx];
        int s  = v & 0xFFFF;
        int dl = (v >> 16) & 0xFF;
        int pos = atomicAdd(&cur[dl], 1);
        psrc[pos] = s;
    }
}

// ---------------- aggregate x[src] per head -> z[n, h*64+i] ----------------
// 4 nodes per wave, 16 lanes per node; float4 gathers; nt z stores.
#define MAXDEG4 64
__global__ void __launch_bounds__(256) aggregate4_k(
    const float* __restrict__ x, const float* __restrict__ asrc,
    const float* __restrict__ adst, const int* __restrict__ row,
    const int* __restrict__ psrc, float* __restrict__ z, int N)
{
    __shared__ float4 pL[16][MAXDEG4 + 1];   // ~16.6 KB, stride 65 -> distinct bank quads
    __shared__ int    sI[16][MAXDEG4 + 1];   // ~4.2 KB
    const int tid  = threadIdx.x;
    const int lane = tid & 63;
    const int g    = lane >> 4;
    const int li   = lane & 15;
    const int slot = (tid >> 6) * 4 + g;     // 0..15
    const int n = blockIdx.x * 16 + slot;
    const bool active = n < N;

    int rs = 0, deg = 0;
    float4 ad = make_float4(0.f, 0.f, 0.f, 0.f);
    if (active) {
        rs  = row[n];
        deg = row[n + 1] - rs;
        ad  = *(const float4*)(adst + 4 * (size_t)n);
    }

    float m0 = -INFINITY, m1 = -INFINITY, m2 = -INFINITY, m3 = -INFINITY;
    float s0 = 0.f, s1 = 0.f, s2 = 0.f, s3 = 0.f;
    float4 a0 = make_float4(0.f,0.f,0.f,0.f), a1 = a0, a2 = a0, a3 = a0;
    const float* xb = x + (size_t)li * 4;

    if (deg <= MAXDEG4) {
        // pass 1: logits -> LDS, per-lane max
        for (int j = li; j < deg; j += 16) {
            int s = psrc[rs + j];
            sI[slot][j] = s;
            float4 a = *(const float4*)(asrc + 4 * (size_t)s);
            float e0 = a.x + ad.x; e0 = e0 > 0.f ? e0 : NEG_SLOPE * e0;
            float e1 = a.y + ad.y; e1 = e1 > 0.f ? e1 : NEG_SLOPE * e1;
            float e2 = a.z + ad.z; e2 = e2 > 0.f ? e2 : NEG_SLOPE * e2;
            float e3 = a.w + ad.w; e3 = e3 > 0.f ? e3 : NEG_SLOPE * e3;
            pL[slot][j] = make_float4(e0, e1, e2, e3);
            m0 = fmaxf(m0, e0); m1 = fmaxf(m1, e1);
            m2 = fmaxf(m2, e2); m3 = fmaxf(m3, e3);
        }
        #pragma unroll
        for (int off = 1; off < 16; off <<= 1) {
            m0 = fmaxf(m0, __shfl_xor(m0, off));
            m1 = fmaxf(m1, __shfl_xor(m1, off));
            m2 = fmaxf(m2, __shfl_xor(m2, off));
            m3 = fmaxf(m3, __shfl_xor(m3, off));
        }
        // pass 2: p = exp(e-m) -> LDS, per-lane sum
        for (int j = li; j < deg; j += 16) {
            float4 e = pL[slot][j];
            float4 p = make_float4(__expf(e.x - m0), __expf(e.y - m1),
                                   __expf(e.z - m2), __expf(e.w - m3));
            pL[slot][j] = p;
            s0 += p.x; s1 += p.y; s2 += p.z; s3 += p.w;
        }
        #pragma unroll
        for (int off = 1; off < 16; off <<= 1) {
            s0 += __shfl_xor(s0, off);
            s1 += __shfl_xor(s1, off);
            s2 += __shfl_xor(s2, off);
            s3 += __shfl_xor(s3, off);
        }
        // pass 3: weighted float4 gather of x[src]
        #pragma unroll 2
        for (int j = 0; j < deg; ++j) {
            int s = sI[slot][j];
            float4 p = pL[slot][j];
            float4 xv = *(const float4*)(xb + (size_t)s * 64);
            a0.x = fmaf(p.x, xv.x, a0.x); a0.y = fmaf(p.x, xv.y, a0.y);
            a0.z = fmaf(p.x, xv.z, a0.z); a0.w = fmaf(p.x, xv.w, a0.w);
            a1.x = fmaf(p.y, xv.x, a1.x); a1.y = fmaf(p.y, xv.y, a1.y);
            a1.z = fmaf(p.y, xv.z, a1.z); a1.w = fmaf(p.y, xv.w, a1.w);
            a2.x = fmaf(p.z, xv.x, a2.x); a2.y = fmaf(p.z, xv.y, a2.y);
            a2.z = fmaf(p.z, xv.z, a2.z); a2.w = fmaf(p.z, xv.w, a2.w);
            a3.x = fmaf(p.w, xv.x, a3.x); a3.y = fmaf(p.w, xv.y, a3.y);
            a3.z = fmaf(p.w, xv.z, a3.z); a3.w = fmaf(p.w, xv.w, a3.w);
        }
    } else {
        // fallback deg > 64 (vanishingly rare): recompute, no LDS
        for (int j = li; j < deg; j += 16) {
            int s = psrc[rs + j];
            float4 a = *(const float4*)(asrc + 4 * (size_t)s);
            float e0 = a.x + ad.x; e0 = e0 > 0.f ? e0 : NEG_SLOPE * e0;
            float e1 = a.y + ad.y; e1 = e1 > 0.f ? e1 : NEG_SLOPE * e1;
            float e2 = a.z + ad.z; e2 = e2 > 0.f ? e2 : NEG_SLOPE * e2;
            float e3 = a.w + ad.w; e3 = e3 > 0.f ? e3 : NEG_SLOPE * e3;
            m0 = fmaxf(m0, e0); m1 = fmaxf(m1, e1);
            m2 = fmaxf(m2, e2); m3 = fmaxf(m3, e3);
        }
        #pragma unroll
        for (int off = 1; off < 16; off <<= 1) {
            m0 = fmaxf(m0, __shfl_xor(m0, off));
            m1 = fmaxf(m1, __shfl_xor(m1, off));
            m2 = fmaxf(m2, __shfl_xor(m2, off));
            m3 = fmaxf(m3, __shfl_xor(m3, off));
        }
        for (int j = li; j < deg; j += 16) {
            int s = psrc[rs + j];
            float4 a = *(const float4*)(asrc + 4 * (size_t)s);
            float e0 = a.x + ad.x; e0 = e0 > 0.f ? e0 : NEG_SLOPE * e0;
            float e1 = a.y + ad.y; e1 = e1 > 0.f ? e1 : NEG_SLOPE * e1;
            float e2 = a.z + ad.z; e2 = e2 > 0.f ? e2 : NEG_SLOPE * e2;
            float e3 = a.w + ad.w; e3 = e3 > 0.f ? e3 : NEG_SLOPE * e3;
            s0 += __expf(e0 - m0); s1 += __expf(e1 - m1);
            s2 += __expf(e2 - m2); s3 += __expf(e3 - m3);
        }
        #pragma unroll
        for (int off = 1; off < 16; off <<= 1) {
            s0 += __shfl_xor(s0, off);
            s1 += __shfl_xor(s1, off);
            s2 += __shfl_xor(s2, off);
            s3 += __shfl_xor(s3, off);
        }
        for (int j = 0; j < deg; ++j) {
            int s = psrc[rs + j];
            float4 a = *(const float4*)(asrc + 4 * (size_t)s);
            float e0 = a.x + ad.x; e0 = e0 > 0.f ? e0 : NEG_SLOPE * e0;
            float e1 = a.y + ad.y; e1 = e1 > 0.f ? e1 : NEG_SLOPE * e1;
            float e2 = a.z + ad.z; e2 = e2 > 0.f ? e2 : NEG_SLOPE * e2;
            float e3 = a.w + ad.w; e3 = e3 > 0.f ? e3 : NEG_SLOPE * e3;
            float p0 = __expf(e0 - m0), p1 = __expf(e1 - m1);
            float p2 = __expf(e2 - m2), p3 = __expf(e3 - m3);
            float4 xv = *(const float4*)(xb + (size_t)s * 64);
            a0.x = fmaf(p0, xv.x, a0.x); a0.y = fmaf(p0, xv.y, a0.y);
            a0.z = fmaf(p0, xv.z, a0.z); a0.w = fmaf(p0, xv.w, a0.w);
            a1.x = fmaf(p1, xv.x, a1.x); a1.y = fmaf(p1, xv.y, a1.y);
            a1.z = fmaf(p1, xv.z, a1.z); a1.w = fmaf(p1, xv.w, a1.w);
            a2.x = fmaf(p2, xv.x, a2.x); a2.y = fmaf(p2, xv.y, a2.y);
            a2.z = fmaf(p2, xv.z, a2.z); a2.w = fmaf(p2, xv.w, a2.w);
            a3.x = fmaf(p3, xv.x, a3.x); a3.y = fmaf(p3, xv.y, a3.y);
            a3.z = fmaf(p3, xv.z, a3.z); a3.w = fmaf(p3, xv.w, a3.w);
        }
    }

    if (active) {
        float i0 = 0.25f / (s0 + EPS_DEN), i1 = 0.25f / (s1 + EPS_DEN);
        float i2 = 0.25f / (s2 + EPS_DEN), i3 = 0.25f / (s3 + EPS_DEN);
        float* zp = z + (size_t)n * 256 + li * 4;
        f4v v0 = {a0.x * i0, a0.y * i0, a0.z * i0, a0.w * i0};
        f4v v1 = {a1.x * i1, a1.y * i1, a1.z * i1, a1.w * i1};
        f4v v2 = {a2.x * i2, a2.y * i2, a2.z * i2, a2.w * i2};
        f4v v3 = {a3.x * i3, a3.y * i3, a3.z * i3, a3.w * i3};
        __builtin_nontemporal_store(v0, (f4v*)(zp));
        __builtin_nontemporal_store(v1, (f4v*)(zp + 64));
        __builtin_nontemporal_store(v2, (f4v*)(zp + 128));
        __builtin_nontemporal_store(v3, (f4v*)(zp + 192));
    }
}

// ---------------- zw: out[n,o] = relu( sum_{h,i} z[n,h,i] W[i,h,o] + b[o] ) ----------------
__global__ void __launch_bounds__(256) zw_k(
    const float* __restrict__ z, const float* __restrict__ W,
    const float* __restrict__ bias, float* __restrict__ out, int N)
{
    __shared__ float zT[64 * 64];  // [k][n^swz] 16 KB
    __shared__ float Ws[64 * 64];  // [i][o]     16 KB
    const int tid = threadIdx.x;
    const int n0  = blockIdx.x * 64;

    const int rgrp = tid >> 4;
    const int cgrp = tid & 15;
    const int r4 = rgrp << 2, c4 = cgrp << 2;

    float acc[4][4];
    #pragma unroll
    for (int i = 0; i < 4; ++i)
        #pragma unroll
        for (int j = 0; j < 4; ++j) acc[i][j] = 0.f;

    for (int c = 0; c < 4; ++c) {
        __syncthreads();
        #pragma unroll
        for (int it = 0; it < 4; ++it) {
            int idx = tid + 256 * it;
            int n   = idx >> 4;
            int k4  = (idx & 15) << 2;
            int gn  = n0 + n;
            f4v v = {0.f, 0.f, 0.f, 0.f};
            if (gn < N)
                v = __builtin_nontemporal_load(
                        (const f4v*)(z + (size_t)gn * 256 + c * 64 + k4));
            int nsw = n ^ (((k4 >> 2) & 7) << 2);
            zT[(k4 + 0) * 64 + nsw] = v[0];
            zT[(k4 + 1) * 64 + nsw] = v[1];
            zT[(k4 + 2) * 64 + nsw] = v[2];
            zT[(k4 + 3) * 64 + nsw] = v[3];
        }
        #pragma unroll
        for (int it = 0; it < 4; ++it) {
            int idx = tid + 256 * it;
            int i   = idx >> 4;
            int o4  = (idx & 15) << 2;
            *(float4*)(Ws + i * 64 + o4) =
                *(const float4*)(W + (size_t)i * 256 + c * 64 + o4);
        }
        __syncthreads();

        #pragma unroll 8
        for (int k = 0; k < 64; ++k) {
            int sw = ((k >> 2) & 7) << 2;
            float4 zv = *(const float4*)(zT + k * 64 + (r4 ^ sw));
            float4 wv = *(const float4*)(Ws + k * 64 + c4);
            float zr[4] = {zv.x, zv.y, zv.z, zv.w};
            float wc[4] = {wv.x, wv.y, wv.z, wv.w};
            #pragma unroll
            for (int i = 0; i < 4; ++i)
                #pragma unroll
                for (int j = 0; j < 4; ++j)
                    acc[i][j] = fmaf(zr[i], wc[j], acc[i][j]);
        }
    }

    float4 b4 = *(const float4*)(bias + c4);
    #pragma unroll
    for (int i = 0; i < 4; ++i) {
        int gn = n0 + r4 + i;
        if (gn < N) {
            float4 o;
            o.x = fmaxf(acc[i][0] + b4.x, 0.f);
            o.y = fmaxf(acc[i][1] + b4.y, 0.f);
            o.z = fmaxf(acc[i][2] + b4.z, 0.f);
            o.w = fmaxf(acc[i][3] + b4.w, 0.f);
            *(float4*)(out + (size_t)gn * 64 + c4) = o;
        }
    }
}

// ---------------- launch ----------------
extern "C" void kernel_launch(void* const* d_in, const int* in_sizes, int n_in,
                              void* d_out, int out_size, void* d_ws, size_t ws_size,
                              hipStream_t stream)
{
    const float* x   = (const float*)d_in[0];
    const int*   ei  = (const int*)d_in[1];
    const float* W1  = (const float*)d_in[4];
    const float* as1 = (const float*)d_in[5];
    const float* ad1 = (const float*)d_in[6];
    const float* b1  = (const float*)d_in[7];
    const float* W2  = (const float*)d_in[8];
    const float* as2 = (const float*)d_in[9];
    const float* ad2 = (const float*)d_in[10];
    const float* b2  = (const float*)d_in[11];

    const int E = in_sizes[1] / 2;
    const int N = N_NODES;
    const int NB = (N + 1023) / 1024;

    char* ws = (char*)d_ws;
    size_t off = 0;
    auto alloc = [&](size_t bytes) -> void* {
        void* p = ws + off;
        off = (off + bytes + 255) & ~(size_t)255;
        return p;
    };
    float*        z     = (float*)alloc((size_t)N * 256 * 4);  // 51.2 MB
    float*        x1    = (float*)alloc((size_t)N * 64 * 4);   // 12.8 MB
    float*        asrc  = (float*)alloc((size_t)N * 4 * 4);
    float*        adst  = (float*)alloc((size_t)N * 4 * 4);
    int*          cnt   = (int*)alloc((size_t)N * 4);
    int*          row   = (int*)alloc((size_t)(N + 1) * 4);
    int*          psrc  = (int*)alloc((size_t)E * 4);
    int*          excl  = (int*)alloc((size_t)N * 4);
    int*          bsum  = (int*)alloc(256 * 4);
    int*          bh    = (int*)alloc((size_t)NBUCK * NBLK * 4);
    int*          boff  = (int*)alloc((size_t)NBUCK * NBLK * 4);
    unsigned int* stage = (unsigned int*)alloc((size_t)E * 4);

    // CSR (shared by both layers)
    zero_k<<<(N + 255) / 256, 256, 0, stream>>>(cnt, N);
    hist_bucket_k<<<NBLK, 256, 0, stream>>>(ei, cnt, bh, E);
    scan1_k<<<NB, 1024, 0, stream>>>(cnt, excl, bsum, N);
    scan2_k<<<1, 64, 0, stream>>>(bsum, NB);
    scan3_k<<<(N + 256) / 256, 256, 0, stream>>>(excl, bsum, row, N, E);
    bscan_k<<<NBUCK, 64, 0, stream>>>(bh, row, boff);
    bplace_k<<<NBLK, 256, 0, stream>>>(ei, boff, stage, E);
    bscatter_k<<<NBUCK, 256, 0, stream>>>(stage, row, psrc, N);

    const int nblk64 = (N + 63) / 64;
    const int nblk16 = (N + 15) / 16;

    // layer 1
    alpha_k<<<nblk64, 256, 0, stream>>>(x, W1, as1, ad1, asrc, adst, N);
    aggregate4_k<<<nblk16, 256, 0, stream>>>(x, asrc, adst, row, psrc, z, N);
    zw_k<<<nblk64, 256, 0, stream>>>(z, W1, b1, x1, N);

    // layer 2
    alpha_k<<<nblk64, 256, 0, stream>>>(x1, W2, as2, ad2, asrc, adst, N);
    aggregate4_k<<<nblk16, 256, 0, stream>>>(x1, asrc, adst, row, psrc, z, N);
    zw_k<<<nblk64, 256, 0, stream>>>(z, W2, b2, (float*)d_out, N);
}

// Round 7
// 257.388 us; speedup vs baseline: 1.0882x; 1.0882x over previous
//
#include <hip/hip_runtime.h>
#include <hip/hip_bf16.h>
#include <math.h>

#define N_NODES 50000
#define NEG_SLOPE 0.2f
#define EPS_DEN 1e-16f

#define NBUCK 196          // ceil(N_NODES / 256)
#define NBLK  512          // edge-pass blocks

typedef float f4v __attribute__((ext_vector_type(4)));

// ---------------- prep: Wa[i][h] = sum_o W[i,h,o]*a[h,o] ----------------
// WaSD[i*8 + h] = src side, WaSD[i*8 + 4 + h] = dst side.
__global__ void __launch_bounds__(256) prep_k(
    const float* __restrict__ W, const float* __restrict__ aS,
    const float* __restrict__ aD, float* __restrict__ WaSD)
{
    int tid = threadIdx.x;
    int h = tid >> 6, i = tid & 63;
    const float* wrow = W + (size_t)i * 256 + h * 64;
    const float* as = aS + h * 64;
    const float* ad = aD + h * 64;
    float ws = 0.f, wd = 0.f;
    #pragma unroll 8
    for (int o = 0; o < 64; ++o) {
        float w = wrow[o];
        ws = fmaf(w, as[o], ws);
        wd = fmaf(w, ad[o], wd);
    }
    WaSD[i * 8 + h]     = ws;
    WaSD[i * 8 + 4 + h] = wd;
}

// ---------------- alpha: asrc/adst[n,h] = x[n,:] . Wa[:,h] ----------------
__global__ void __launch_bounds__(256) alpha_k(
    const float* __restrict__ x, const float* __restrict__ WaSD,
    float* __restrict__ asrc, float* __restrict__ adst, int N)
{
    __shared__ float Wl[512];   // [i*8 + side*4 + h]  2 KB
    int tid = threadIdx.x;
    Wl[tid]       = WaSD[tid];
    Wl[tid + 256] = WaSD[tid + 256];
    __syncthreads();

    int node = blockIdx.x * 64 + (tid >> 2);
    int q = tid & 3;
    if (node >= N) return;

    float pS[4] = {0.f, 0.f, 0.f, 0.f};
    float pD[4] = {0.f, 0.f, 0.f, 0.f};
    const float* xp = x + (size_t)node * 64 + q * 16;
    #pragma unroll
    for (int j = 0; j < 4; ++j) {
        float4 xv = *(const float4*)(xp + j * 4);
        float xr[4] = {xv.x, xv.y, xv.z, xv.w};
        #pragma unroll
        for (int u = 0; u < 4; ++u) {
            int i = q * 16 + j * 4 + u;
            float4 wS = *(const float4*)(Wl + i * 8);
            float4 wD = *(const float4*)(Wl + i * 8 + 4);
            pS[0] = fmaf(xr[u], wS.x, pS[0]); pS[1] = fmaf(xr[u], wS.y, pS[1]);
            pS[2] = fmaf(xr[u], wS.z, pS[2]); pS[3] = fmaf(xr[u], wS.w, pS[3]);
            pD[0] = fmaf(xr[u], wD.x, pD[0]); pD[1] = fmaf(xr[u], wD.y, pD[1]);
            pD[2] = fmaf(xr[u], wD.z, pD[2]); pD[3] = fmaf(xr[u], wD.w, pD[3]);
        }
    }
    #pragma unroll
    for (int off = 1; off <= 2; off <<= 1) {
        #pragma unroll
        for (int h = 0; h < 4; ++h) {
            pS[h] += __shfl_xor(pS[h], off);
            pD[h] += __shfl_xor(pD[h], off);
        }
    }
    if (q == 0) {
        *(float4*)(asrc + 4 * (size_t)node) = make_float4(pS[0], pS[1], pS[2], pS[3]);
        *(float4*)(adst + 4 * (size_t)node) = make_float4(pD[0], pD[1], pD[2], pD[3]);
    }
}

// ---------------- CSR build ----------------
__global__ void zero_k(int* __restrict__ p, int n) {
    int i = blockIdx.x * blockDim.x + threadIdx.x;
    if (i < n) p[i] = 0;
}

__global__ void __launch_bounds__(256) hist_bucket_k(
    const int* __restrict__ ei, int* __restrict__ cnt, int* __restrict__ bh, int E)
{
    __shared__ int lh[NBUCK];
    int tid = threadIdx.x;
    for (int b = tid; b < NBUCK; b += 256) lh[b] = 0;
    __syncthreads();

    const int ch = (E + NBLK - 1) / NBLK;
    const int e0 = blockIdx.x * ch;
    const int e1 = min(e0 + ch, E);
    for (int e = e0 + tid; e < e1; e += 256) {
        int d = ei[E + e];
        atomicAdd(&cnt[d], 1);
        atomicAdd(&lh[d >> 8], 1);
    }
    __syncthreads();
    for (int b = tid; b < NBUCK; b += 256)
        bh[(size_t)b * NBLK + blockIdx.x] = lh[b];
}

__global__ void __launch_bounds__(1024) scan1_k(
    const int* __restrict__ cnt, int* __restrict__ excl, int* __restrict__ bsum, int n)
{
    __shared__ int sd[1024];
    int tid = threadIdx.x;
    int i = blockIdx.x * 1024 + tid;
    int v = (i < n) ? cnt[i] : 0;
    sd[tid] = v;
    __syncthreads();
    for (int off = 1; off < 1024; off <<= 1) {
        int t = (tid >= off) ? sd[tid - off] : 0;
        __syncthreads();
        sd[tid] += t;
        __syncthreads();
    }
    if (i < n) excl[i] = sd[tid] - v;
    if (tid == 1023) bsum[blockIdx.x] = sd[1023];
}

__global__ void scan2_k(int* __restrict__ bsum, int nb) {
    if (threadIdx.x == 0 && blockIdx.x == 0) {
        int acc = 0;
        for (int i = 0; i < nb; ++i) { int t = bsum[i]; bsum[i] = acc; acc += t; }
    }
}

__global__ void scan3_k(const int* __restrict__ excl, const int* __restrict__ bsum,
                        int* __restrict__ row, int n, int E)
{
    int i = blockIdx.x * blockDim.x + threadIdx.x;
    if (i < n) row[i] = excl[i] + bsum[i >> 10];
    if (i == n) row[n] = E;
}

__global__ void __launch_bounds__(64) bscan_k(
    const int* __restrict__ bh, const int* __restrict__ row,
    int* __restrict__ boff)
{
    const int b = blockIdx.x;
    const int lane = threadIdx.x;
    int v[8];
    int base = b * NBLK;
    #pragma unroll
    for (int u = 0; u < 8; ++u) v[u] = bh[base + lane * 8 + u];
    int t = 0;
    #pragma unroll
    for (int u = 0; u < 8; ++u) t += v[u];
    int run = t;
    #pragma unroll
    for (int off = 1; off < 64; off <<= 1) {
        int u = __shfl_up(run, off);
        if (lane >= off) run += u;
    }
    int lane_base = row[b << 8] + run - t;
    #pragma unroll
    for (int u = 0; u < 8; ++u) {
        boff[base + lane * 8 + u] = lane_base;
        lane_base += v[u];
    }
}

__global__ void __launch_bounds__(256) bplace_k(
    const int* __restrict__ ei, const int* __restrict__ boff,
    unsigned int* __restrict__ stage, int E)
{
    __shared__ int cur[NBUCK];
    int tid = threadIdx.x;
    for (int b = tid; b < NBUCK; b += 256)
        cur[b] = boff[(size_t)b * NBLK + blockIdx.x];
    __syncthreads();

    const int ch = (E + NBLK - 1) / NBLK;
    const int e0 = blockIdx.x * ch;
    const int e1 = min(e0 + ch, E);
    for (int e = e0 + tid; e < e1; e += 256) {
        int s = ei[e];
        int d = ei[E + e];
        int pos = atomicAdd(&cur[d >> 8], 1);
        stage[pos] = (unsigned int)s | ((unsigned int)(d & 255) << 16);
    }
}

__global__ void __launch_bounds__(256) bscatter_k(
    const unsigned int* __restrict__ stage, const int* __restrict__ row,
    int* __restrict__ psrc, int N)
{
    __shared__ int cur[256];
    const int b = blockIdx.x;
    const int tid = threadIdx.x;
    const int nb0 = b << 8;
    int node = nb0 + tid;
    cur[tid] = (node < N) ? row[node] : 0;
    __syncthreads();

    const int es = row[nb0];
    const int ee = row[min(nb0 + 256, N)];
    for (int idx = es + tid; idx < ee; idx += 256) {
        unsigned int v = stage[idx];
        int s  = v & 0xFFFF;
        int dl = (v >> 16) & 0xFF;
        int pos = atomicAdd(&cur[dl], 1);
        psrc[pos] = s;
    }
}

// ---------------- aggregate x[src] per head -> z[n, h*64+i] ----------------
// 4 nodes per wave, 16 lanes per node; float4 gathers; nt z stores.
#define MAXDEG4 64
__global__ void __launch_bounds__(256) aggregate4_k(
    const float* __restrict__ x, const float* __restrict__ asrc,
    const float* __restrict__ adst, const int* __restrict__ row,
    const int* __restrict__ psrc, float* __restrict__ z, int N)
{
    __shared__ float4 pL[16][MAXDEG4 + 1];
    __shared__ int    sI[16][MAXDEG4 + 1];
    const int tid  = threadIdx.x;
    const int lane = tid & 63;
    const int g    = lane >> 4;
    const int li   = lane & 15;
    const int slot = (tid >> 6) * 4 + g;
    const int n = blockIdx.x * 16 + slot;
    const bool active = n < N;

    int rs = 0, deg = 0;
    float4 ad = make_float4(0.f, 0.f, 0.f, 0.f);
    if (active) {
        rs  = row[n];
        deg = row[n + 1] - rs;
        ad  = *(const float4*)(adst + 4 * (size_t)n);
    }

    float m0 = -INFINITY, m1 = -INFINITY, m2 = -INFINITY, m3 = -INFINITY;
    float s0 = 0.f, s1 = 0.f, s2 = 0.f, s3 = 0.f;
    float4 a0 = make_float4(0.f,0.f,0.f,0.f), a1 = a0, a2 = a0, a3 = a0;
    const float* xb = x + (size_t)li * 4;

    if (deg <= MAXDEG4) {
        for (int j = li; j < deg; j += 16) {
            int s = psrc[rs + j];
            sI[slot][j] = s;
            float4 a = *(const float4*)(asrc + 4 * (size_t)s);
            float e0 = a.x + ad.x; e0 = e0 > 0.f ? e0 : NEG_SLOPE * e0;
            float e1 = a.y + ad.y; e1 = e1 > 0.f ? e1 : NEG_SLOPE * e1;
            float e2 = a.z + ad.z; e2 = e2 > 0.f ? e2 : NEG_SLOPE * e2;
            float e3 = a.w + ad.w; e3 = e3 > 0.f ? e3 : NEG_SLOPE * e3;
            pL[slot][j] = make_float4(e0, e1, e2, e3);
            m0 = fmaxf(m0, e0); m1 = fmaxf(m1, e1);
            m2 = fmaxf(m2, e2); m3 = fmaxf(m3, e3);
        }
        #pragma unroll
        for (int off = 1; off < 16; off <<= 1) {
            m0 = fmaxf(m0, __shfl_xor(m0, off));
            m1 = fmaxf(m1, __shfl_xor(m1, off));
            m2 = fmaxf(m2, __shfl_xor(m2, off));
            m3 = fmaxf(m3, __shfl_xor(m3, off));
        }
        for (int j = li; j < deg; j += 16) {
            float4 e = pL[slot][j];
            float4 p = make_float4(__expf(e.x - m0), __expf(e.y - m1),
                                   __expf(e.z - m2), __expf(e.w - m3));
            pL[slot][j] = p;
            s0 += p.x; s1 += p.y; s2 += p.z; s3 += p.w;
        }
        #pragma unroll
        for (int off = 1; off < 16; off <<= 1) {
            s0 += __shfl_xor(s0, off);
            s1 += __shfl_xor(s1, off);
            s2 += __shfl_xor(s2, off);
            s3 += __shfl_xor(s3, off);
        }
        #pragma unroll 2
        for (int j = 0; j < deg; ++j) {
            int s = sI[slot][j];
            float4 p = pL[slot][j];
            float4 xv = *(const float4*)(xb + (size_t)s * 64);
            a0.x = fmaf(p.x, xv.x, a0.x); a0.y = fmaf(p.x, xv.y, a0.y);
            a0.z = fmaf(p.x, xv.z, a0.z); a0.w = fmaf(p.x, xv.w, a0.w);
            a1.x = fmaf(p.y, xv.x, a1.x); a1.y = fmaf(p.y, xv.y, a1.y);
            a1.z = fmaf(p.y, xv.z, a1.z); a1.w = fmaf(p.y, xv.w, a1.w);
            a2.x = fmaf(p.z, xv.x, a2.x); a2.y = fmaf(p.z, xv.y, a2.y);
            a2.z = fmaf(p.z, xv.z, a2.z); a2.w = fmaf(p.z, xv.w, a2.w);
            a3.x = fmaf(p.w, xv.x, a3.x); a3.y = fmaf(p.w, xv.y, a3.y);
            a3.z = fmaf(p.w, xv.z, a3.z); a3.w = fmaf(p.w, xv.w, a3.w);
        }
    } else {
        for (int j = li; j < deg; j += 16) {
            int s = psrc[rs + j];
            float4 a = *(const float4*)(asrc + 4 * (size_t)s);
            float e0 = a.x + ad.x; e0 = e0 > 0.f ? e0 : NEG_SLOPE * e0;
            float e1 = a.y + ad.y; e1 = e1 > 0.f ? e1 : NEG_SLOPE * e1;
            float e2 = a.z + ad.z; e2 = e2 > 0.f ? e2 : NEG_SLOPE * e2;
            float e3 = a.w + ad.w; e3 = e3 > 0.f ? e3 : NEG_SLOPE * e3;
            m0 = fmaxf(m0, e0); m1 = fmaxf(m1, e1);
            m2 = fmaxf(m2, e2); m3 = fmaxf(m3, e3);
        }
        #pragma unroll
        for (int off = 1; off < 16; off <<= 1) {
            m0 = fmaxf(m0, __shfl_xor(m0, off));
            m1 = fmaxf(m1, __shfl_xor(m1, off));
            m2 = fmaxf(m2, __shfl_xor(m2, off));
            m3 = fmaxf(m3, __shfl_xor(m3, off));
        }
        for (int j = li; j < deg; j += 16) {
            int s = psrc[rs + j];
            float4 a = *(const float4*)(asrc + 4 * (size_t)s);
            float e0 = a.x + ad.x; e0 = e0 > 0.f ? e0 : NEG_SLOPE * e0;
            float e1 = a.y + ad.y; e1 = e1 > 0.f ? e1 : NEG_SLOPE * e1;
            float e2 = a.z + ad.z; e2 = e2 > 0.f ? e2 : NEG_SLOPE * e2;
            float e3 = a.w + ad.w; e3 = e3 > 0.f ? e3 : NEG_SLOPE * e3;
            s0 += __expf(e0 - m0); s1 += __expf(e1 - m1);
            s2 += __expf(e2 - m2); s3 += __expf(e3 - m3);
        }
        #pragma unroll
        for (int off = 1; off < 16; off <<= 1) {
            s0 += __shfl_xor(s0, off);
            s1 += __shfl_xor(s1, off);
            s2 += __shfl_xor(s2, off);
            s3 += __shfl_xor(s3, off);
        }
        for (int j = 0; j < deg; ++j) {
            int s = psrc[rs + j];
            float4 a = *(const float4*)(asrc + 4 * (size_t)s);
            float e0 = a.x + ad.x; e0 = e0 > 0.f ? e0 : NEG_SLOPE * e0;
            float e1 = a.y + ad.y; e1 = e1 > 0.f ? e1 : NEG_SLOPE * e1;
            float e2 = a.z + ad.z; e2 = e2 > 0.f ? e2 : NEG_SLOPE * e2;
            float e3 = a.w + ad.w; e3 = e3 > 0.f ? e3 : NEG_SLOPE * e3;
            float p0 = __expf(e0 - m0), p1 = __expf(e1 - m1);
            float p2 = __expf(e2 - m2), p3 = __expf(e3 - m3);
            float4 xv = *(const float4*)(xb + (size_t)s * 64);
            a0.x = fmaf(p0, xv.x, a0.x); a0.y = fmaf(p0, xv.y, a0.y);
            a0.z = fmaf(p0, xv.z, a0.z); a0.w = fmaf(p0, xv.w, a0.w);
            a1.x = fmaf(p1, xv.x, a1.x); a1.y = fmaf(p1, xv.y, a1.y);
            a1.z = fmaf(p1, xv.z, a1.z); a1.w = fmaf(p1, xv.w, a1.w);
            a2.x = fmaf(p2, xv.x, a2.x); a2.y = fmaf(p2, xv.y, a2.y);
            a2.z = fmaf(p2, xv.z, a2.z); a2.w = fmaf(p2, xv.w, a2.w);
            a3.x = fmaf(p3, xv.x, a3.x); a3.y = fmaf(p3, xv.y, a3.y);
            a3.z = fmaf(p3, xv.z, a3.z); a3.w = fmaf(p3, xv.w, a3.w);
        }
    }

    if (active) {
        float i0 = 0.25f / (s0 + EPS_DEN), i1 = 0.25f / (s1 + EPS_DEN);
        float i2 = 0.25f / (s2 + EPS_DEN), i3 = 0.25f / (s3 + EPS_DEN);
        float* zp = z + (size_t)n * 256 + li * 4;
        f4v v0 = {a0.x * i0, a0.y * i0, a0.z * i0, a0.w * i0};
        f4v v1 = {a1.x * i1, a1.y * i1, a1.z * i1, a1.w * i1};
        f4v v2 = {a2.x * i2, a2.y * i2, a2.z * i2, a2.w * i2};
        f4v v3 = {a3.x * i3, a3.y * i3, a3.z * i3, a3.w * i3};
        __builtin_nontemporal_store(v0, (f4v*)(zp));
        __builtin_nontemporal_store(v1, (f4v*)(zp + 64));
        __builtin_nontemporal_store(v2, (f4v*)(zp + 128));
        __builtin_nontemporal_store(v3, (f4v*)(zp + 192));
    }
}

// ---------------- zw: out[n,o] = relu( sum_{h,i} z[n,h,i] W[i,h,o] + b[o] ) ----------------
// 64x64 tile, K=256 in 4 chunks of 64; DOUBLE-BUFFERED staging: one sync/chunk.
__global__ void __launch_bounds__(256) zw_k(
    const float* __restrict__ z, const float* __restrict__ W,
    const float* __restrict__ bias, float* __restrict__ out, int N)
{
    __shared__ float zT[2][64 * 64];  // [k][n^swz] 2x16 KB
    __shared__ float Ws[2][64 * 64];  // [i][o]     2x16 KB
    const int tid = threadIdx.x;
    const int n0  = blockIdx.x * 64;

    const int rgrp = tid >> 4;
    const int cgrp = tid & 15;
    const int r4 = rgrp << 2, c4 = cgrp << 2;

    float acc[4][4];
    #pragma unroll
    for (int i = 0; i < 4; ++i)
        #pragma unroll
        for (int j = 0; j < 4; ++j) acc[i][j] = 0.f;

    auto stage = [&](int c, int buf) {
        #pragma unroll
        for (int it = 0; it < 4; ++it) {
            int idx = tid + 256 * it;
            int n   = idx >> 4;
            int k4  = (idx & 15) << 2;
            int gn  = n0 + n;
            f4v v = {0.f, 0.f, 0.f, 0.f};
            if (gn < N)
                v = __builtin_nontemporal_load(
                        (const f4v*)(z + (size_t)gn * 256 + c * 64 + k4));
            int nsw = n ^ (((k4 >> 2) & 7) << 2);
            zT[buf][(k4 + 0) * 64 + nsw] = v[0];
            zT[buf][(k4 + 1) * 64 + nsw] = v[1];
            zT[buf][(k4 + 2) * 64 + nsw] = v[2];
            zT[buf][(k4 + 3) * 64 + nsw] = v[3];
        }
        #pragma unroll
        for (int it = 0; it < 4; ++it) {
            int idx = tid + 256 * it;
            int i   = idx >> 4;
            int o4  = (idx & 15) << 2;
            *(float4*)(Ws[buf] + i * 64 + o4) =
                *(const float4*)(W + (size_t)i * 256 + c * 64 + o4);
        }
    };

    stage(0, 0);
    __syncthreads();

    for (int c = 0; c < 4; ++c) {
        const int buf = c & 1;
        if (c < 3) stage(c + 1, buf ^ 1);   // prefetch next chunk; no wait

        #pragma unroll 8
        for (int k = 0; k < 64; ++k) {
            int sw = ((k >> 2) & 7) << 2;
            float4 zv = *(const float4*)(zT[buf] + k * 64 + (r4 ^ sw));
            float4 wv = *(const float4*)(Ws[buf] + k * 64 + c4);
            float zr[4] = {zv.x, zv.y, zv.z, zv.w};
            float wc[4] = {wv.x, wv.y, wv.z, wv.w};
            #pragma unroll
            for (int i = 0; i < 4; ++i)
                #pragma unroll
                for (int j = 0; j < 4; ++j)
                    acc[i][j] = fmaf(zr[i], wc[j], acc[i][j]);
        }
        __syncthreads();   // staged c+1 complete AND all reads of buf done
    }

    float4 b4 = *(const float4*)(bias + c4);
    #pragma unroll
    for (int i = 0; i < 4; ++i) {
        int gn = n0 + r4 + i;
        if (gn < N) {
            float4 o;
            o.x = fmaxf(acc[i][0] + b4.x, 0.f);
            o.y = fmaxf(acc[i][1] + b4.y, 0.f);
            o.z = fmaxf(acc[i][2] + b4.z, 0.f);
            o.w = fmaxf(acc[i][3] + b4.w, 0.f);
            *(float4*)(out + (size_t)gn * 64 + c4) = o;
        }
    }
}

// ---------------- launch ----------------
extern "C" void kernel_launch(void* const* d_in, const int* in_sizes, int n_in,
                              void* d_out, int out_size, void* d_ws, size_t ws_size,
                              hipStream_t stream)
{
    const float* x   = (const float*)d_in[0];
    const int*   ei  = (const int*)d_in[1];
    const float* W1  = (const float*)d_in[4];
    const float* as1 = (const float*)d_in[5];
    const float* ad1 = (const float*)d_in[6];
    const float* b1  = (const float*)d_in[7];
    const float* W2  = (const float*)d_in[8];
    const float* as2 = (const float*)d_in[9];
    const float* ad2 = (const float*)d_in[10];
    const float* b2  = (const float*)d_in[11];

    const int E = in_sizes[1] / 2;
    const int N = N_NODES;
    const int NB = (N + 1023) / 1024;

    char* ws = (char*)d_ws;
    size_t off = 0;
    auto alloc = [&](size_t bytes) -> void* {
        void* p = ws + off;
        off = (off + bytes + 255) & ~(size_t)255;
        return p;
    };
    float*        z     = (float*)alloc((size_t)N * 256 * 4);
    float*        x1    = (float*)alloc((size_t)N * 64 * 4);
    float*        asrc  = (float*)alloc((size_t)N * 4 * 4);
    float*        adst  = (float*)alloc((size_t)N * 4 * 4);
    float*        WaSD  = (float*)alloc(64 * 8 * 4);
    int*          cnt   = (int*)alloc((size_t)N * 4);
    int*          row   = (int*)alloc((size_t)(N + 1) * 4);
    int*          psrc  = (int*)alloc((size_t)E * 4);
    int*          excl  = (int*)alloc((size_t)N * 4);
    int*          bsum  = (int*)alloc(256 * 4);
    int*          bh    = (int*)alloc((size_t)NBUCK * NBLK * 4);
    int*          boff  = (int*)alloc((size_t)NBUCK * NBLK * 4);
    unsigned int* stage = (unsigned int*)alloc((size_t)E * 4);

    // CSR (shared by both layers)
    zero_k<<<(N + 255) / 256, 256, 0, stream>>>(cnt, N);
    hist_bucket_k<<<NBLK, 256, 0, stream>>>(ei, cnt, bh, E);
    scan1_k<<<NB, 1024, 0, stream>>>(cnt, excl, bsum, N);
    scan2_k<<<1, 64, 0, stream>>>(bsum, NB);
    scan3_k<<<(N + 256) / 256, 256, 0, stream>>>(excl, bsum, row, N, E);
    bscan_k<<<NBUCK, 64, 0, stream>>>(bh, row, boff);
    bplace_k<<<NBLK, 256, 0, stream>>>(ei, boff, stage, E);
    bscatter_k<<<NBUCK, 256, 0, stream>>>(stage, row, psrc, N);

    const int nblk64 = (N + 63) / 64;
    const int nblk16 = (N + 15) / 16;

    // layer 1
    prep_k<<<1, 256, 0, stream>>>(W1, as1, ad1, WaSD);
    alpha_k<<<nblk64, 256, 0, stream>>>(x, WaSD, asrc, adst, N);
    aggregate4_k<<<nblk16, 256, 0, stream>>>(x, asrc, adst, row, psrc, z, N);
    zw_k<<<nblk64, 256, 0, stream>>>(z, W1, b1, x1, N);

    // layer 2
    prep_k<<<1, 256, 0, stream>>>(W2, as2, ad2, WaSD);
    alpha_k<<<nblk64, 256, 0, stream>>>(x1, WaSD, asrc, adst, N);
    aggregate4_k<<<nblk16, 256, 0, stream>>>(x1, asrc, adst, row, psrc, z, N);
    zw_k<<<nblk64, 256, 0, stream>>>(z, W2, b2, (float*)d_out, N);
}

// Round 8
// 251.247 us; speedup vs baseline: 1.1148x; 1.0244x over previous
//
#include <hip/hip_runtime.h>
#include <hip/hip_bf16.h>
#include <math.h>

#define N_NODES 50000
#define NEG_SLOPE 0.2f
#define EPS_DEN 1e-16f

#define NBUCK 196          // ceil(N_NODES / 256)
#define NBLK  512          // edge-pass blocks

typedef float f4v __attribute__((ext_vector_type(4)));

// ---------------- prep: Wa[i][h] = sum_o W[i,h,o]*a[h,o] ----------------
__global__ void __launch_bounds__(256) prep_k(
    const float* __restrict__ W, const float* __restrict__ aS,
    const float* __restrict__ aD, float* __restrict__ WaSD)
{
    int tid = threadIdx.x;
    int h = tid >> 6, i = tid & 63;
    const float* wrow = W + (size_t)i * 256 + h * 64;
    const float* as = aS + h * 64;
    const float* ad = aD + h * 64;
    float ws = 0.f, wd = 0.f;
    #pragma unroll 8
    for (int o = 0; o < 64; ++o) {
        float w = wrow[o];
        ws = fmaf(w, as[o], ws);
        wd = fmaf(w, ad[o], wd);
    }
    WaSD[i * 8 + h]     = ws;
    WaSD[i * 8 + 4 + h] = wd;
}

// ---------------- alpha: asrc/adst[n,h] = x[n,:] . Wa[:,h] ----------------
__global__ void __launch_bounds__(256) alpha_k(
    const float* __restrict__ x, const float* __restrict__ WaSD,
    float* __restrict__ asrc, float* __restrict__ adst, int N)
{
    __shared__ float Wl[512];
    int tid = threadIdx.x;
    Wl[tid]       = WaSD[tid];
    Wl[tid + 256] = WaSD[tid + 256];
    __syncthreads();

    int node = blockIdx.x * 64 + (tid >> 2);
    int q = tid & 3;
    if (node >= N) return;

    float pS[4] = {0.f, 0.f, 0.f, 0.f};
    float pD[4] = {0.f, 0.f, 0.f, 0.f};
    const float* xp = x + (size_t)node * 64 + q * 16;
    #pragma unroll
    for (int j = 0; j < 4; ++j) {
        float4 xv = *(const float4*)(xp + j * 4);
        float xr[4] = {xv.x, xv.y, xv.z, xv.w};
        #pragma unroll
        for (int u = 0; u < 4; ++u) {
            int i = q * 16 + j * 4 + u;
            float4 wS = *(const float4*)(Wl + i * 8);
            float4 wD = *(const float4*)(Wl + i * 8 + 4);
            pS[0] = fmaf(xr[u], wS.x, pS[0]); pS[1] = fmaf(xr[u], wS.y, pS[1]);
            pS[2] = fmaf(xr[u], wS.z, pS[2]); pS[3] = fmaf(xr[u], wS.w, pS[3]);
            pD[0] = fmaf(xr[u], wD.x, pD[0]); pD[1] = fmaf(xr[u], wD.y, pD[1]);
            pD[2] = fmaf(xr[u], wD.z, pD[2]); pD[3] = fmaf(xr[u], wD.w, pD[3]);
        }
    }
    #pragma unroll
    for (int off = 1; off <= 2; off <<= 1) {
        #pragma unroll
        for (int h = 0; h < 4; ++h) {
            pS[h] += __shfl_xor(pS[h], off);
            pD[h] += __shfl_xor(pD[h], off);
        }
    }
    if (q == 0) {
        *(float4*)(asrc + 4 * (size_t)node) = make_float4(pS[0], pS[1], pS[2], pS[3]);
        *(float4*)(adst + 4 * (size_t)node) = make_float4(pD[0], pD[1], pD[2], pD[3]);
    }
}

// ---------------- CSR build (atomic-light bucketed counting sort) ----------------
// bucket b = dst>>8 owns nodes [b*256, (b+1)*256) and a contiguous psrc range.

// per-block bucket histogram, LDS only (no global atomics)
__global__ void __launch_bounds__(256) hist_bucket_k(
    const int* __restrict__ ei, int* __restrict__ bh, int E)
{
    __shared__ int lh[NBUCK];
    int tid = threadIdx.x;
    for (int b = tid; b < NBUCK; b += 256) lh[b] = 0;
    __syncthreads();

    const int ch = (E + NBLK - 1) / NBLK;
    const int e0 = blockIdx.x * ch;
    const int e1 = min(e0 + ch, E);
    for (int e = e0 + tid; e < e1; e += 256)
        atomicAdd(&lh[ei[E + e] >> 8], 1);
    __syncthreads();
    for (int b = tid; b < NBUCK; b += 256)
        bh[(size_t)b * NBLK + blockIdx.x] = lh[b];
}

// per-bucket LOCAL exclusive prefix over the NBLK block counts + bucket total
__global__ void __launch_bounds__(64) bscan_k(
    const int* __restrict__ bh, int* __restrict__ boffL, int* __restrict__ btot)
{
    const int b = blockIdx.x;
    const int lane = threadIdx.x;
    int v[8];
    int base = b * NBLK;
    #pragma unroll
    for (int u = 0; u < 8; ++u) v[u] = bh[base + lane * 8 + u];
    int t = 0;
    #pragma unroll
    for (int u = 0; u < 8; ++u) t += v[u];
    int run = t;
    #pragma unroll
    for (int off = 1; off < 64; off <<= 1) {
        int u = __shfl_up(run, off);
        if (lane >= off) run += u;
    }
    int lane_base = run - t;          // exclusive, local to bucket
    #pragma unroll
    for (int u = 0; u < 8; ++u) {
        boffL[base + lane * 8 + u] = lane_base;
        lane_base += v[u];
    }
    if (lane == 63) btot[b] = run;    // bucket total
}

// exclusive scan over the 196 bucket totals -> bbase; bbase[NBUCK]=E, row[N]=E
__global__ void __launch_bounds__(256) btot_k(
    const int* __restrict__ btot, int* __restrict__ bbase,
    int* __restrict__ row, int N, int E)
{
    __shared__ int sd[256];
    int tid = threadIdx.x;
    int v = (tid < NBUCK) ? btot[tid] : 0;
    sd[tid] = v;
    __syncthreads();
    for (int off = 1; off < 256; off <<= 1) {
        int t = (tid >= off) ? sd[tid - off] : 0;
        __syncthreads();
        sd[tid] += t;
        __syncthreads();
    }
    if (tid < NBUCK) bbase[tid] = sd[tid] - v;
    if (tid == 0) { bbase[NBUCK] = E; row[N] = E; }
}

// place edges into bucket-grouped staging (LDS cursors, no global atomics)
__global__ void __launch_bounds__(256) bplace_k(
    const int* __restrict__ ei, const int* __restrict__ bbase,
    const int* __restrict__ boffL, unsigned int* __restrict__ stage, int E)
{
    __shared__ int cur[NBUCK];
    int tid = threadIdx.x;
    for (int b = tid; b < NBUCK; b += 256)
        cur[b] = bbase[b] + boffL[(size_t)b * NBLK + blockIdx.x];
    __syncthreads();

    const int ch = (E + NBLK - 1) / NBLK;
    const int e0 = blockIdx.x * ch;
    const int e1 = min(e0 + ch, E);
    for (int e = e0 + tid; e < e1; e += 256) {
        int s = ei[e];
        int d = ei[E + e];
        int pos = atomicAdd(&cur[d >> 8], 1);
        stage[pos] = (unsigned int)s | ((unsigned int)(d & 255) << 16);
    }
}

// per-bucket: count per node (LDS), scan 256, emit row[] AND scatter psrc.
__global__ void __launch_bounds__(256) bscatter_k(
    const unsigned int* __restrict__ stage, const int* __restrict__ bbase,
    int* __restrict__ row, int* __restrict__ psrc, int N)
{
    __shared__ int cnt[256];
    __shared__ int sd[256];
    __shared__ int cur[256];
    const int b = blockIdx.x;
    const int tid = threadIdx.x;
    const int nb0 = b << 8;
    const int es = bbase[b], ee = bbase[b + 1];

    cnt[tid] = 0;
    __syncthreads();
    for (int idx = es + tid; idx < ee; idx += 256)
        atomicAdd(&cnt[(stage[idx] >> 16) & 255], 1);
    __syncthreads();

    int v = cnt[tid];
    sd[tid] = v;
    __syncthreads();
    for (int off = 1; off < 256; off <<= 1) {
        int t = (tid >= off) ? sd[tid - off] : 0;
        __syncthreads();
        sd[tid] += t;
        __syncthreads();
    }
    int r = es + sd[tid] - v;      // exclusive
    int node = nb0 + tid;
    if (node < N) row[node] = r;
    cur[tid] = r;
    __syncthreads();

    for (int idx = es + tid; idx < ee; idx += 256) {
        unsigned int w = stage[idx];
        int pos = atomicAdd(&cur[(w >> 16) & 255], 1);
        psrc[pos] = w & 0xFFFF;
    }
}

// ---------------- aggregate x[src] per head -> z[n, h*64+i] ----------------
#define MAXDEG4 64
__global__ void __launch_bounds__(256) aggregate4_k(
    const float* __restrict__ x, const float* __restrict__ asrc,
    const float* __restrict__ adst, const int* __restrict__ row,
    const int* __restrict__ psrc, float* __restrict__ z, int N)
{
    __shared__ float4 pL[16][MAXDEG4 + 1];
    __shared__ int    sI[16][MAXDEG4 + 1];
    const int tid  = threadIdx.x;
    const int lane = tid & 63;
    const int g    = lane >> 4;
    const int li   = lane & 15;
    const int slot = (tid >> 6) * 4 + g;
    const int n = blockIdx.x * 16 + slot;
    const bool active = n < N;

    int rs = 0, deg = 0;
    float4 ad = make_float4(0.f, 0.f, 0.f, 0.f);
    if (active) {
        rs  = row[n];
        deg = row[n + 1] - rs;
        ad  = *(const float4*)(adst + 4 * (size_t)n);
    }

    float m0 = -INFINITY, m1 = -INFINITY, m2 = -INFINITY, m3 = -INFINITY;
    float s0 = 0.f, s1 = 0.f, s2 = 0.f, s3 = 0.f;
    float4 a0 = make_float4(0.f,0.f,0.f,0.f), a1 = a0, a2 = a0, a3 = a0;
    const float* xb = x + (size_t)li * 4;

    if (deg <= MAXDEG4) {
        for (int j = li; j < deg; j += 16) {
            int s = psrc[rs + j];
            sI[slot][j] = s;
            float4 a = *(const float4*)(asrc + 4 * (size_t)s);
            float e0 = a.x + ad.x; e0 = e0 > 0.f ? e0 : NEG_SLOPE * e0;
            float e1 = a.y + ad.y; e1 = e1 > 0.f ? e1 : NEG_SLOPE * e1;
            float e2 = a.z + ad.z; e2 = e2 > 0.f ? e2 : NEG_SLOPE * e2;
            float e3 = a.w + ad.w; e3 = e3 > 0.f ? e3 : NEG_SLOPE * e3;
            pL[slot][j] = make_float4(e0, e1, e2, e3);
            m0 = fmaxf(m0, e0); m1 = fmaxf(m1, e1);
            m2 = fmaxf(m2, e2); m3 = fmaxf(m3, e3);
        }
        #pragma unroll
        for (int off = 1; off < 16; off <<= 1) {
            m0 = fmaxf(m0, __shfl_xor(m0, off));
            m1 = fmaxf(m1, __shfl_xor(m1, off));
            m2 = fmaxf(m2, __shfl_xor(m2, off));
            m3 = fmaxf(m3, __shfl_xor(m3, off));
        }
        for (int j = li; j < deg; j += 16) {
            float4 e = pL[slot][j];
            float4 p = make_float4(__expf(e.x - m0), __expf(e.y - m1),
                                   __expf(e.z - m2), __expf(e.w - m3));
            pL[slot][j] = p;
            s0 += p.x; s1 += p.y; s2 += p.z; s3 += p.w;
        }
        #pragma unroll
        for (int off = 1; off < 16; off <<= 1) {
            s0 += __shfl_xor(s0, off);
            s1 += __shfl_xor(s1, off);
            s2 += __shfl_xor(s2, off);
            s3 += __shfl_xor(s3, off);
        }
        #pragma unroll 2
        for (int j = 0; j < deg; ++j) {
            int s = sI[slot][j];
            float4 p = pL[slot][j];
            float4 xv = *(const float4*)(xb + (size_t)s * 64);
            a0.x = fmaf(p.x, xv.x, a0.x); a0.y = fmaf(p.x, xv.y, a0.y);
            a0.z = fmaf(p.x, xv.z, a0.z); a0.w = fmaf(p.x, xv.w, a0.w);
            a1.x = fmaf(p.y, xv.x, a1.x); a1.y = fmaf(p.y, xv.y, a1.y);
            a1.z = fmaf(p.y, xv.z, a1.z); a1.w = fmaf(p.y, xv.w, a1.w);
            a2.x = fmaf(p.z, xv.x, a2.x); a2.y = fmaf(p.z, xv.y, a2.y);
            a2.z = fmaf(p.z, xv.z, a2.z); a2.w = fmaf(p.z, xv.w, a2.w);
            a3.x = fmaf(p.w, xv.x, a3.x); a3.y = fmaf(p.w, xv.y, a3.y);
            a3.z = fmaf(p.w, xv.z, a3.z); a3.w = fmaf(p.w, xv.w, a3.w);
        }
    } else {
        for (int j = li; j < deg; j += 16) {
            int s = psrc[rs + j];
            float4 a = *(const float4*)(asrc + 4 * (size_t)s);
            float e0 = a.x + ad.x; e0 = e0 > 0.f ? e0 : NEG_SLOPE * e0;
            float e1 = a.y + ad.y; e1 = e1 > 0.f ? e1 : NEG_SLOPE * e1;
            float e2 = a.z + ad.z; e2 = e2 > 0.f ? e2 : NEG_SLOPE * e2;
            float e3 = a.w + ad.w; e3 = e3 > 0.f ? e3 : NEG_SLOPE * e3;
            m0 = fmaxf(m0, e0); m1 = fmaxf(m1, e1);
            m2 = fmaxf(m2, e2); m3 = fmaxf(m3, e3);
        }
        #pragma unroll
        for (int off = 1; off < 16; off <<= 1) {
            m0 = fmaxf(m0, __shfl_xor(m0, off));
            m1 = fmaxf(m1, __shfl_xor(m1, off));
            m2 = fmaxf(m2, __shfl_xor(m2, off));
            m3 = fmaxf(m3, __shfl_xor(m3, off));
        }
        for (int j = li; j < deg; j += 16) {
            int s = psrc[rs + j];
            float4 a = *(const float4*)(asrc + 4 * (size_t)s);
            float e0 = a.x + ad.x; e0 = e0 > 0.f ? e0 : NEG_SLOPE * e0;
            float e1 = a.y + ad.y; e1 = e1 > 0.f ? e1 : NEG_SLOPE * e1;
            float e2 = a.z + ad.z; e2 = e2 > 0.f ? e2 : NEG_SLOPE * e2;
            float e3 = a.w + ad.w; e3 = e3 > 0.f ? e3 : NEG_SLOPE * e3;
            s0 += __expf(e0 - m0); s1 += __expf(e1 - m1);
            s2 += __expf(e2 - m2); s3 += __expf(e3 - m3);
        }
        #pragma unroll
        for (int off = 1; off < 16; off <<= 1) {
            s0 += __shfl_xor(s0, off);
            s1 += __shfl_xor(s1, off);
            s2 += __shfl_xor(s2, off);
            s3 += __shfl_xor(s3, off);
        }
        for (int j = 0; j < deg; ++j) {
            int s = psrc[rs + j];
            float4 a = *(const float4*)(asrc + 4 * (size_t)s);
            float e0 = a.x + ad.x; e0 = e0 > 0.f ? e0 : NEG_SLOPE * e0;
            float e1 = a.y + ad.y; e1 = e1 > 0.f ? e1 : NEG_SLOPE * e1;
            float e2 = a.z + ad.z; e2 = e2 > 0.f ? e2 : NEG_SLOPE * e2;
            float e3 = a.w + ad.w; e3 = e3 > 0.f ? e3 : NEG_SLOPE * e3;
            float p0 = __expf(e0 - m0), p1 = __expf(e1 - m1);
            float p2 = __expf(e2 - m2), p3 = __expf(e3 - m3);
            float4 xv = *(const float4*)(xb + (size_t)s * 64);
            a0.x = fmaf(p0, xv.x, a0.x); a0.y = fmaf(p0, xv.y, a0.y);
            a0.z = fmaf(p0, xv.z, a0.z); a0.w = fmaf(p0, xv.w, a0.w);
            a1.x = fmaf(p1, xv.x, a1.x); a1.y = fmaf(p1, xv.y, a1.y);
            a1.z = fmaf(p1, xv.z, a1.z); a1.w = fmaf(p1, xv.w, a1.w);
            a2.x = fmaf(p2, xv.x, a2.x); a2.y = fmaf(p2, xv.y, a2.y);
            a2.z = fmaf(p2, xv.z, a2.z); a2.w = fmaf(p2, xv.w, a2.w);
            a3.x = fmaf(p3, xv.x, a3.x); a3.y = fmaf(p3, xv.y, a3.y);
            a3.z = fmaf(p3, xv.z, a3.z); a3.w = fmaf(p3, xv.w, a3.w);
        }
    }

    if (active) {
        float i0 = 0.25f / (s0 + EPS_DEN), i1 = 0.25f / (s1 + EPS_DEN);
        float i2 = 0.25f / (s2 + EPS_DEN), i3 = 0.25f / (s3 + EPS_DEN);
        float* zp = z + (size_t)n * 256 + li * 4;
        f4v v0 = {a0.x * i0, a0.y * i0, a0.z * i0, a0.w * i0};
        f4v v1 = {a1.x * i1, a1.y * i1, a1.z * i1, a1.w * i1};
        f4v v2 = {a2.x * i2, a2.y * i2, a2.z * i2, a2.w * i2};
        f4v v3 = {a3.x * i3, a3.y * i3, a3.z * i3, a3.w * i3};
        __builtin_nontemporal_store(v0, (f4v*)(zp));
        __builtin_nontemporal_store(v1, (f4v*)(zp + 64));
        __builtin_nontemporal_store(v2, (f4v*)(zp + 128));
        __builtin_nontemporal_store(v3, (f4v*)(zp + 192));
    }
}

// ---------------- zw: out[n,o] = relu( sum_{h,i} z[n,h,i] W[i,h,o] + b[o] ) ----------------
// ONE WAVE per block (syncthreads free), 64x64 tile, 8x8 acc (1 B LDS / FMA),
// K=256 in 4 chunks, single 32 KB buffer -> 5 blocks/CU.
__global__ void __launch_bounds__(64) zw_k(
    const float* __restrict__ z, const float* __restrict__ W,
    const float* __restrict__ bias, float* __restrict__ out, int N)
{
    __shared__ float zT[64 * 64];  // [k][n^swz] 16 KB
    __shared__ float Ws[64 * 64];  // [i][o]     16 KB
    const int tid = threadIdx.x;   // 0..63
    const int n0  = blockIdx.x * 64;

    const int r8 = (tid >> 3) << 3;   // 8 row groups
    const int c8 = (tid & 7) << 3;    // 8 col groups

    float acc[8][8];
    #pragma unroll
    for (int i = 0; i < 8; ++i)
        #pragma unroll
        for (int j = 0; j < 8; ++j) acc[i][j] = 0.f;

    for (int c = 0; c < 4; ++c) {
        __syncthreads();   // 1 wave: compiles to a waitcnt only
        #pragma unroll
        for (int it = 0; it < 16; ++it) {
            int idx = tid + 64 * it;          // 0..1023 float4
            int n   = idx >> 4;
            int k4  = (idx & 15) << 2;
            int gn  = n0 + n;
            f4v v = {0.f, 0.f, 0.f, 0.f};
            if (gn < N)
                v = __builtin_nontemporal_load(
                        (const f4v*)(z + (size_t)gn * 256 + c * 64 + k4));
            int nsw = n ^ (((k4 >> 2) & 7) << 2);
            zT[(k4 + 0) * 64 + nsw] = v[0];
            zT[(k4 + 1) * 64 + nsw] = v[1];
            zT[(k4 + 2) * 64 + nsw] = v[2];
            zT[(k4 + 3) * 64 + nsw] = v[3];
        }
        #pragma unroll
        for (int it = 0; it < 16; ++it) {
            int idx = tid + 64 * it;
            int i   = idx >> 4;
            int o4  = (idx & 15) << 2;
            *(float4*)(Ws + i * 64 + o4) =
                *(const float4*)(W + (size_t)i * 256 + c * 64 + o4);
        }
        __syncthreads();

        #pragma unroll 2
        for (int k = 0; k < 64; ++k) {
            int sw = ((k >> 2) & 7) << 2;
            int cb = r8 ^ sw;
            float4 za = *(const float4*)(zT + k * 64 + cb);
            float4 zb = *(const float4*)(zT + k * 64 + (cb ^ 4));
            float4 wa = *(const float4*)(Ws + k * 64 + c8);
            float4 wb = *(const float4*)(Ws + k * 64 + c8 + 4);
            float zr[8] = {za.x, za.y, za.z, za.w, zb.x, zb.y, zb.z, zb.w};
            float wc[8] = {wa.x, wa.y, wa.z, wa.w, wb.x, wb.y, wb.z, wb.w};
            #pragma unroll
            for (int i = 0; i < 8; ++i)
                #pragma unroll
                for (int j = 0; j < 8; ++j)
                    acc[i][j] = fmaf(zr[i], wc[j], acc[i][j]);
        }
    }

    float4 ba = *(const float4*)(bias + c8);
    float4 bb = *(const float4*)(bias + c8 + 4);
    #pragma unroll
    for (int i = 0; i < 8; ++i) {
        int gn = n0 + r8 + i;
        if (gn < N) {
            float4 o0, o1;
            o0.x = fmaxf(acc[i][0] + ba.x, 0.f);
            o0.y = fmaxf(acc[i][1] + ba.y, 0.f);
            o0.z = fmaxf(acc[i][2] + ba.z, 0.f);
            o0.w = fmaxf(acc[i][3] + ba.w, 0.f);
            o1.x = fmaxf(acc[i][4] + bb.x, 0.f);
            o1.y = fmaxf(acc[i][5] + bb.y, 0.f);
            o1.z = fmaxf(acc[i][6] + bb.z, 0.f);
            o1.w = fmaxf(acc[i][7] + bb.w, 0.f);
            *(float4*)(out + (size_t)gn * 64 + c8)     = o0;
            *(float4*)(out + (size_t)gn * 64 + c8 + 4) = o1;
        }
    }
}

// ---------------- launch ----------------
extern "C" void kernel_launch(void* const* d_in, const int* in_sizes, int n_in,
                              void* d_out, int out_size, void* d_ws, size_t ws_size,
                              hipStream_t stream)
{
    const float* x   = (const float*)d_in[0];
    const int*   ei  = (const int*)d_in[1];
    const float* W1  = (const float*)d_in[4];
    const float* as1 = (const float*)d_in[5];
    const float* ad1 = (const float*)d_in[6];
    const float* b1  = (const float*)d_in[7];
    const float* W2  = (const float*)d_in[8];
    const float* as2 = (const float*)d_in[9];
    const float* ad2 = (const float*)d_in[10];
    const float* b2  = (const float*)d_in[11];

    const int E = in_sizes[1] / 2;
    const int N = N_NODES;

    char* ws = (char*)d_ws;
    size_t off = 0;
    auto alloc = [&](size_t bytes) -> void* {
        void* p = ws + off;
        off = (off + bytes + 255) & ~(size_t)255;
        return p;
    };
    float*        z     = (float*)alloc((size_t)N * 256 * 4);
    float*        x1    = (float*)alloc((size_t)N * 64 * 4);
    float*        asrc  = (float*)alloc((size_t)N * 4 * 4);
    float*        adst  = (float*)alloc((size_t)N * 4 * 4);
    float*        WaSD  = (float*)alloc(64 * 8 * 4);
    int*          row   = (int*)alloc((size_t)(N + 1) * 4);
    int*          psrc  = (int*)alloc((size_t)E * 4);
    int*          bh    = (int*)alloc((size_t)NBUCK * NBLK * 4);
    int*          boffL = (int*)alloc((size_t)NBUCK * NBLK * 4);
    int*          btot  = (int*)alloc((NBUCK + 1) * 4);
    int*          bbase = (int*)alloc((NBUCK + 1) * 4);
    unsigned int* stage = (unsigned int*)alloc((size_t)E * 4);

    // CSR (shared by both layers)
    hist_bucket_k<<<NBLK, 256, 0, stream>>>(ei, bh, E);
    bscan_k<<<NBUCK, 64, 0, stream>>>(bh, boffL, btot);
    btot_k<<<1, 256, 0, stream>>>(btot, bbase, row, N, E);
    bplace_k<<<NBLK, 256, 0, stream>>>(ei, bbase, boffL, stage, E);
    bscatter_k<<<NBUCK, 256, 0, stream>>>(stage, bbase, row, psrc, N);

    const int nblk64 = (N + 63) / 64;
    const int nblk16 = (N + 15) / 16;

    // layer 1
    prep_k<<<1, 256, 0, stream>>>(W1, as1, ad1, WaSD);
    alpha_k<<<nblk64, 256, 0, stream>>>(x, WaSD, asrc, adst, N);
    aggregate4_k<<<nblk16, 256, 0, stream>>>(x, asrc, adst, row, psrc, z, N);
    zw_k<<<nblk64, 64, 0, stream>>>(z, W1, b1, x1, N);

    // layer 2
    prep_k<<<1, 256, 0, stream>>>(W2, as2, ad2, WaSD);
    alpha_k<<<nblk64, 256, 0, stream>>>(x1, WaSD, asrc, adst, N);
    aggregate4_k<<<nblk16, 256, 0, stream>>>(x1, asrc, adst, row, psrc, z, N);
    zw_k<<<nblk64, 64, 0, stream>>>(z, W2, b2, (float*)d_out, N);
}

// Round 9
// 184.827 us; speedup vs baseline: 1.5155x; 1.3594x over previous
//
#include <hip/hip_runtime.h>
#include <hip/hip_bf16.h>
#include <math.h>

#define N_NODES 50000
#define NEG_SLOPE 0.2f
#define EPS_DEN 1e-16f

#define NBUCK 196          // ceil(N_NODES / 256)
#define NBLK  512          // edge-pass blocks

typedef float f4v __attribute__((ext_vector_type(4)));

// ---------------- prep: Wa[i][h] = sum_o W[i,h,o]*a[h,o] ----------------
__global__ void __launch_bounds__(256) prep_k(
    const float* __restrict__ W, const float* __restrict__ aS,
    const float* __restrict__ aD, float* __restrict__ WaSD)
{
    int tid = threadIdx.x;
    int h = tid >> 6, i = tid & 63;
    const float* wrow = W + (size_t)i * 256 + h * 64;
    const float* as = aS + h * 64;
    const float* ad = aD + h * 64;
    float ws = 0.f, wd = 0.f;
    #pragma unroll 8
    for (int o = 0; o < 64; ++o) {
        float w = wrow[o];
        ws = fmaf(w, as[o], ws);
        wd = fmaf(w, ad[o], wd);
    }
    WaSD[i * 8 + h]     = ws;
    WaSD[i * 8 + 4 + h] = wd;
}

// ---------------- alpha: asrc/adst[n,h] = x[n,:] . Wa[:,h] ----------------
__global__ void __launch_bounds__(256) alpha_k(
    const float* __restrict__ x, const float* __restrict__ WaSD,
    float* __restrict__ asrc, float* __restrict__ adst, int N)
{
    __shared__ float Wl[512];
    int tid = threadIdx.x;
    Wl[tid]       = WaSD[tid];
    Wl[tid + 256] = WaSD[tid + 256];
    __syncthreads();

    int node = blockIdx.x * 64 + (tid >> 2);
    int q = tid & 3;
    if (node >= N) return;

    float pS[4] = {0.f, 0.f, 0.f, 0.f};
    float pD[4] = {0.f, 0.f, 0.f, 0.f};
    const float* xp = x + (size_t)node * 64 + q * 16;
    #pragma unroll
    for (int j = 0; j < 4; ++j) {
        float4 xv = *(const float4*)(xp + j * 4);
        float xr[4] = {xv.x, xv.y, xv.z, xv.w};
        #pragma unroll
        for (int u = 0; u < 4; ++u) {
            int i = q * 16 + j * 4 + u;
            float4 wS = *(const float4*)(Wl + i * 8);
            float4 wD = *(const float4*)(Wl + i * 8 + 4);
            pS[0] = fmaf(xr[u], wS.x, pS[0]); pS[1] = fmaf(xr[u], wS.y, pS[1]);
            pS[2] = fmaf(xr[u], wS.z, pS[2]); pS[3] = fmaf(xr[u], wS.w, pS[3]);
            pD[0] = fmaf(xr[u], wD.x, pD[0]); pD[1] = fmaf(xr[u], wD.y, pD[1]);
            pD[2] = fmaf(xr[u], wD.z, pD[2]); pD[3] = fmaf(xr[u], wD.w, pD[3]);
        }
    }
    #pragma unroll
    for (int off = 1; off <= 2; off <<= 1) {
        #pragma unroll
        for (int h = 0; h < 4; ++h) {
            pS[h] += __shfl_xor(pS[h], off);
            pD[h] += __shfl_xor(pD[h], off);
        }
    }
    if (q == 0) {
        *(float4*)(asrc + 4 * (size_t)node) = make_float4(pS[0], pS[1], pS[2], pS[3]);
        *(float4*)(adst + 4 * (size_t)node) = make_float4(pD[0], pD[1], pD[2], pD[3]);
    }
}

// ---------------- CSR build (atomic-light bucketed counting sort) ----------------
__global__ void __launch_bounds__(256) hist_bucket_k(
    const int* __restrict__ ei, int* __restrict__ bh, int E)
{
    __shared__ int lh[NBUCK];
    int tid = threadIdx.x;
    for (int b = tid; b < NBUCK; b += 256) lh[b] = 0;
    __syncthreads();

    const int ch = (E + NBLK - 1) / NBLK;
    const int e0 = blockIdx.x * ch;
    const int e1 = min(e0 + ch, E);
    for (int e = e0 + tid; e < e1; e += 256)
        atomicAdd(&lh[ei[E + e] >> 8], 1);
    __syncthreads();
    for (int b = tid; b < NBUCK; b += 256)
        bh[(size_t)b * NBLK + blockIdx.x] = lh[b];
}

__global__ void __launch_bounds__(64) bscan_k(
    const int* __restrict__ bh, int* __restrict__ boffL, int* __restrict__ btot)
{
    const int b = blockIdx.x;
    const int lane = threadIdx.x;
    int v[8];
    int base = b * NBLK;
    #pragma unroll
    for (int u = 0; u < 8; ++u) v[u] = bh[base + lane * 8 + u];
    int t = 0;
    #pragma unroll
    for (int u = 0; u < 8; ++u) t += v[u];
    int run = t;
    #pragma unroll
    for (int off = 1; off < 64; off <<= 1) {
        int u = __shfl_up(run, off);
        if (lane >= off) run += u;
    }
    int lane_base = run - t;
    #pragma unroll
    for (int u = 0; u < 8; ++u) {
        boffL[base + lane * 8 + u] = lane_base;
        lane_base += v[u];
    }
    if (lane == 63) btot[b] = run;
}

__global__ void __launch_bounds__(256) btot_k(
    const int* __restrict__ btot, int* __restrict__ bbase,
    int* __restrict__ row, int N, int E)
{
    __shared__ int sd[256];
    int tid = threadIdx.x;
    int v = (tid < NBUCK) ? btot[tid] : 0;
    sd[tid] = v;
    __syncthreads();
    for (int off = 1; off < 256; off <<= 1) {
        int t = (tid >= off) ? sd[tid - off] : 0;
        __syncthreads();
        sd[tid] += t;
        __syncthreads();
    }
    if (tid < NBUCK) bbase[tid] = sd[tid] - v;
    if (tid == 0) { bbase[NBUCK] = E; row[N] = E; }
}

__global__ void __launch_bounds__(256) bplace_k(
    const int* __restrict__ ei, const int* __restrict__ bbase,
    const int* __restrict__ boffL, unsigned int* __restrict__ stage, int E)
{
    __shared__ int cur[NBUCK];
    int tid = threadIdx.x;
    for (int b = tid; b < NBUCK; b += 256)
        cur[b] = bbase[b] + boffL[(size_t)b * NBLK + blockIdx.x];
    __syncthreads();

    const int ch = (E + NBLK - 1) / NBLK;
    const int e0 = blockIdx.x * ch;
    const int e1 = min(e0 + ch, E);
    for (int e = e0 + tid; e < e1; e += 256) {
        int s = ei[e];
        int d = ei[E + e];
        int pos = atomicAdd(&cur[d >> 8], 1);
        stage[pos] = (unsigned int)s | ((unsigned int)(d & 255) << 16);
    }
}

__global__ void __launch_bounds__(256) bscatter_k(
    const unsigned int* __restrict__ stage, const int* __restrict__ bbase,
    int* __restrict__ row, int* __restrict__ psrc, int N)
{
    __shared__ int cnt[256];
    __shared__ int sd[256];
    __shared__ int cur[256];
    const int b = blockIdx.x;
    const int tid = threadIdx.x;
    const int nb0 = b << 8;
    const int es = bbase[b], ee = bbase[b + 1];

    cnt[tid] = 0;
    __syncthreads();
    for (int idx = es + tid; idx < ee; idx += 256)
        atomicAdd(&cnt[(stage[idx] >> 16) & 255], 1);
    __syncthreads();

    int v = cnt[tid];
    sd[tid] = v;
    __syncthreads();
    for (int off = 1; off < 256; off <<= 1) {
        int t = (tid >= off) ? sd[tid - off] : 0;
        __syncthreads();
        sd[tid] += t;
        __syncthreads();
    }
    int r = es + sd[tid] - v;
    int node = nb0 + tid;
    if (node < N) row[node] = r;
    cur[tid] = r;
    __syncthreads();

    for (int idx = es + tid; idx < ee; idx += 256) {
        unsigned int w = stage[idx];
        int pos = atomicAdd(&cur[(w >> 16) & 255], 1);
        psrc[pos] = w & 0xFFFF;
    }
}

// ---------------- FUSED aggregate + (z.W) + bias + relu ----------------
// Block = 256 threads = 16 nodes x 16 lanes.
// Phase 1 (aggregate4): z[n] built in registers, written to LDS zt.
// Phase 2: out tile [16 x 64] = zt [16 x 256] . W' [256 x 64], W chunked in LDS.
// LDS: pL 16.6KB | sI 4.2KB | zt 16.6KB  (Wc aliases pL in phase 2) = 37.4 KB
#define MAXDEG4 64
#define ZT_STRIDE 260
__global__ void __launch_bounds__(256) aggzw_k(
    const float* __restrict__ x, const float* __restrict__ asrc,
    const float* __restrict__ adst, const int* __restrict__ row,
    const int* __restrict__ psrc, const float* __restrict__ W,
    const float* __restrict__ bias, float* __restrict__ out, int N)
{
    __shared__ float smem[9360];
    float4* pL = (float4*)smem;                 // [slot*65 + j], 1040 float4
    int*    sI = (int*)(smem + 4160);           // [slot*65 + j], 1040 int
    float*  zt = smem + 5200;                   // [slot*ZT_STRIDE + c], 4160 f
    float*  Wc = smem;                          // phase-2 alias of pL (4096 f)

    const int tid  = threadIdx.x;
    const int lane = tid & 63;
    const int li   = lane & 15;
    const int slot = tid >> 4;                  // 0..15 (== node within block)
    const int n = blockIdx.x * 16 + slot;
    const bool active = n < N;

    int rs = 0, deg = 0;
    float4 ad = make_float4(0.f, 0.f, 0.f, 0.f);
    if (active) {
        rs  = row[n];
        deg = row[n + 1] - rs;
        ad  = *(const float4*)(adst + 4 * (size_t)n);
    }

    float m0 = -INFINITY, m1 = -INFINITY, m2 = -INFINITY, m3 = -INFINITY;
    float s0 = 0.f, s1 = 0.f, s2 = 0.f, s3 = 0.f;
    float4 a0 = make_float4(0.f,0.f,0.f,0.f), a1 = a0, a2 = a0, a3 = a0;
    const float* xb = x + (size_t)li * 4;

    if (deg <= MAXDEG4) {
        for (int j = li; j < deg; j += 16) {
            int s = psrc[rs + j];
            sI[slot * 65 + j] = s;
            float4 a = *(const float4*)(asrc + 4 * (size_t)s);
            float e0 = a.x + ad.x; e0 = e0 > 0.f ? e0 : NEG_SLOPE * e0;
            float e1 = a.y + ad.y; e1 = e1 > 0.f ? e1 : NEG_SLOPE * e1;
            float e2 = a.z + ad.z; e2 = e2 > 0.f ? e2 : NEG_SLOPE * e2;
            float e3 = a.w + ad.w; e3 = e3 > 0.f ? e3 : NEG_SLOPE * e3;
            pL[slot * 65 + j] = make_float4(e0, e1, e2, e3);
            m0 = fmaxf(m0, e0); m1 = fmaxf(m1, e1);
            m2 = fmaxf(m2, e2); m3 = fmaxf(m3, e3);
        }
        #pragma unroll
        for (int off = 1; off < 16; off <<= 1) {
            m0 = fmaxf(m0, __shfl_xor(m0, off));
            m1 = fmaxf(m1, __shfl_xor(m1, off));
            m2 = fmaxf(m2, __shfl_xor(m2, off));
            m3 = fmaxf(m3, __shfl_xor(m3, off));
        }
        for (int j = li; j < deg; j += 16) {
            float4 e = pL[slot * 65 + j];
            float4 p = make_float4(__expf(e.x - m0), __expf(e.y - m1),
                                   __expf(e.z - m2), __expf(e.w - m3));
            pL[slot * 65 + j] = p;
            s0 += p.x; s1 += p.y; s2 += p.z; s3 += p.w;
        }
        #pragma unroll
        for (int off = 1; off < 16; off <<= 1) {
            s0 += __shfl_xor(s0, off);
            s1 += __shfl_xor(s1, off);
            s2 += __shfl_xor(s2, off);
            s3 += __shfl_xor(s3, off);
        }
        #pragma unroll 2
        for (int j = 0; j < deg; ++j) {
            int s = sI[slot * 65 + j];
            float4 p = pL[slot * 65 + j];
            float4 xv = *(const float4*)(xb + (size_t)s * 64);
            a0.x = fmaf(p.x, xv.x, a0.x); a0.y = fmaf(p.x, xv.y, a0.y);
            a0.z = fmaf(p.x, xv.z, a0.z); a0.w = fmaf(p.x, xv.w, a0.w);
            a1.x = fmaf(p.y, xv.x, a1.x); a1.y = fmaf(p.y, xv.y, a1.y);
            a1.z = fmaf(p.y, xv.z, a1.z); a1.w = fmaf(p.y, xv.w, a1.w);
            a2.x = fmaf(p.z, xv.x, a2.x); a2.y = fmaf(p.z, xv.y, a2.y);
            a2.z = fmaf(p.z, xv.z, a2.z); a2.w = fmaf(p.z, xv.w, a2.w);
            a3.x = fmaf(p.w, xv.x, a3.x); a3.y = fmaf(p.w, xv.y, a3.y);
            a3.z = fmaf(p.w, xv.z, a3.z); a3.w = fmaf(p.w, xv.w, a3.w);
        }
    } else {
        // fallback deg > 64: recompute, no LDS
        for (int j = li; j < deg; j += 16) {
            int s = psrc[rs + j];
            float4 a = *(const float4*)(asrc + 4 * (size_t)s);
            float e0 = a.x + ad.x; e0 = e0 > 0.f ? e0 : NEG_SLOPE * e0;
            float e1 = a.y + ad.y; e1 = e1 > 0.f ? e1 : NEG_SLOPE * e1;
            float e2 = a.z + ad.z; e2 = e2 > 0.f ? e2 : NEG_SLOPE * e2;
            float e3 = a.w + ad.w; e3 = e3 > 0.f ? e3 : NEG_SLOPE * e3;
            m0 = fmaxf(m0, e0); m1 = fmaxf(m1, e1);
            m2 = fmaxf(m2, e2); m3 = fmaxf(m3, e3);
        }
        #pragma unroll
        for (int off = 1; off < 16; off <<= 1) {
            m0 = fmaxf(m0, __shfl_xor(m0, off));
            m1 = fmaxf(m1, __shfl_xor(m1, off));
            m2 = fmaxf(m2, __shfl_xor(m2, off));
            m3 = fmaxf(m3, __shfl_xor(m3, off));
        }
        for (int j = li; j < deg; j += 16) {
            int s = psrc[rs + j];
            float4 a = *(const float4*)(asrc + 4 * (size_t)s);
            float e0 = a.x + ad.x; e0 = e0 > 0.f ? e0 : NEG_SLOPE * e0;
            float e1 = a.y + ad.y; e1 = e1 > 0.f ? e1 : NEG_SLOPE * e1;
            float e2 = a.z + ad.z; e2 = e2 > 0.f ? e2 : NEG_SLOPE * e2;
            float e3 = a.w + ad.w; e3 = e3 > 0.f ? e3 : NEG_SLOPE * e3;
            s0 += __expf(e0 - m0); s1 += __expf(e1 - m1);
            s2 += __expf(e2 - m2); s3 += __expf(e3 - m3);
        }
        #pragma unroll
        for (int off = 1; off < 16; off <<= 1) {
            s0 += __shfl_xor(s0, off);
            s1 += __shfl_xor(s1, off);
            s2 += __shfl_xor(s2, off);
            s3 += __shfl_xor(s3, off);
        }
        for (int j = 0; j < deg; ++j) {
            int s = psrc[rs + j];
            float4 a = *(const float4*)(asrc + 4 * (size_t)s);
            float e0 = a.x + ad.x; e0 = e0 > 0.f ? e0 : NEG_SLOPE * e0;
            float e1 = a.y + ad.y; e1 = e1 > 0.f ? e1 : NEG_SLOPE * e1;
            float e2 = a.z + ad.z; e2 = e2 > 0.f ? e2 : NEG_SLOPE * e2;
            float e3 = a.w + ad.w; e3 = e3 > 0.f ? e3 : NEG_SLOPE * e3;
            float p0 = __expf(e0 - m0), p1 = __expf(e1 - m1);
            float p2 = __expf(e2 - m2), p3 = __expf(e3 - m3);
            float4 xv = *(const float4*)(xb + (size_t)s * 64);
            a0.x = fmaf(p0, xv.x, a0.x); a0.y = fmaf(p0, xv.y, a0.y);
            a0.z = fmaf(p0, xv.z, a0.z); a0.w = fmaf(p0, xv.w, a0.w);
            a1.x = fmaf(p1, xv.x, a1.x); a1.y = fmaf(p1, xv.y, a1.y);
            a1.z = fmaf(p1, xv.z, a1.z); a1.w = fmaf(p1, xv.w, a1.w);
            a2.x = fmaf(p2, xv.x, a2.x); a2.y = fmaf(p2, xv.y, a2.y);
            a2.z = fmaf(p2, xv.z, a2.z); a2.w = fmaf(p2, xv.w, a2.w);
            a3.x = fmaf(p3, xv.x, a3.x); a3.y = fmaf(p3, xv.y, a3.y);
            a3.z = fmaf(p3, xv.z, a3.z); a3.w = fmaf(p3, xv.w, a3.w);
        }
    }

    // z[n, h*64 + li*4 .. +3] -> zt (registers -> LDS; softmax denom folded)
    {
        float i0 = 0.25f / (s0 + EPS_DEN), i1 = 0.25f / (s1 + EPS_DEN);
        float i2 = 0.25f / (s2 + EPS_DEN), i3 = 0.25f / (s3 + EPS_DEN);
        float* zp = zt + slot * ZT_STRIDE + li * 4;
        *(float4*)(zp)       = make_float4(a0.x*i0, a0.y*i0, a0.z*i0, a0.w*i0);
        *(float4*)(zp + 64)  = make_float4(a1.x*i1, a1.y*i1, a1.z*i1, a1.w*i1);
        *(float4*)(zp + 128) = make_float4(a2.x*i2, a2.y*i2, a2.z*i2, a2.w*i2);
        *(float4*)(zp + 192) = make_float4(a3.x*i3, a3.y*i3, a3.z*i3, a3.w*i3);
    }

    // ---------------- phase 2: out[16x64] = zt[16x256] . W'[256x64] ----------------
    const int og = tid & 15;          // out col group (4 cols)
    const int nl = tid >> 4;          // node row (== slot)
    float acc[4] = {0.f, 0.f, 0.f, 0.f};

    for (int cc = 0; cc < 4; ++cc) {
        __syncthreads();              // pL/zt reads done; Wc safe to (re)write
        #pragma unroll
        for (int it = 0; it < 4; ++it) {
            int idx = tid + 256 * it;         // 0..1023 float4
            int k   = idx >> 4;
            int o4  = (idx & 15) << 2;
            *(float4*)(Wc + k * 64 + o4) =
                *(const float4*)(W + (size_t)k * 256 + cc * 64 + o4);
        }
        __syncthreads();

        const float* zrow = zt + nl * ZT_STRIDE + cc * 64;
        #pragma unroll
        for (int k4 = 0; k4 < 16; ++k4) {
            float4 zq = *(const float4*)(zrow + k4 * 4);
            float zr[4] = {zq.x, zq.y, zq.z, zq.w};
            #pragma unroll
            for (int u = 0; u < 4; ++u) {
                float4 wv = *(const float4*)(Wc + (k4 * 4 + u) * 64 + og * 4);
                acc[0] = fmaf(zr[u], wv.x, acc[0]);
                acc[1] = fmaf(zr[u], wv.y, acc[1]);
                acc[2] = fmaf(zr[u], wv.z, acc[2]);
                acc[3] = fmaf(zr[u], wv.w, acc[3]);
            }
        }
    }

    int gn = blockIdx.x * 16 + nl;
    if (gn < N) {
        float4 b4 = *(const float4*)(bias + og * 4);
        float4 o;
        o.x = fmaxf(acc[0] + b4.x, 0.f);
        o.y = fmaxf(acc[1] + b4.y, 0.f);
        o.z = fmaxf(acc[2] + b4.z, 0.f);
        o.w = fmaxf(acc[3] + b4.w, 0.f);
        *(float4*)(out + (size_t)gn * 64 + og * 4) = o;
    }
}

// ---------------- launch ----------------
extern "C" void kernel_launch(void* const* d_in, const int* in_sizes, int n_in,
                              void* d_out, int out_size, void* d_ws, size_t ws_size,
                              hipStream_t stream)
{
    const float* x   = (const float*)d_in[0];
    const int*   ei  = (const int*)d_in[1];
    const float* W1  = (const float*)d_in[4];
    const float* as1 = (const float*)d_in[5];
    const float* ad1 = (const float*)d_in[6];
    const float* b1  = (const float*)d_in[7];
    const float* W2  = (const float*)d_in[8];
    const float* as2 = (const float*)d_in[9];
    const float* ad2 = (const float*)d_in[10];
    const float* b2  = (const float*)d_in[11];

    const int E = in_sizes[1] / 2;
    const int N = N_NODES;

    char* ws = (char*)d_ws;
    size_t off = 0;
    auto alloc = [&](size_t bytes) -> void* {
        void* p = ws + off;
        off = (off + bytes + 255) & ~(size_t)255;
        return p;
    };
    float*        x1    = (float*)alloc((size_t)N * 64 * 4);
    float*        asrc  = (float*)alloc((size_t)N * 4 * 4);
    float*        adst  = (float*)alloc((size_t)N * 4 * 4);
    float*        WaSD  = (float*)alloc(64 * 8 * 4);
    int*          row   = (int*)alloc((size_t)(N + 1) * 4);
    int*          psrc  = (int*)alloc((size_t)E * 4);
    int*          bh    = (int*)alloc((size_t)NBUCK * NBLK * 4);
    int*          boffL = (int*)alloc((size_t)NBUCK * NBLK * 4);
    int*          btot  = (int*)alloc((NBUCK + 1) * 4);
    int*          bbase = (int*)alloc((NBUCK + 1) * 4);
    unsigned int* stage = (unsigned int*)alloc((size_t)E * 4);

    // CSR (shared by both layers)
    hist_bucket_k<<<NBLK, 256, 0, stream>>>(ei, bh, E);
    bscan_k<<<NBUCK, 64, 0, stream>>>(bh, boffL, btot);
    btot_k<<<1, 256, 0, stream>>>(btot, bbase, row, N, E);
    bplace_k<<<NBLK, 256, 0, stream>>>(ei, bbase, boffL, stage, E);
    bscatter_k<<<NBUCK, 256, 0, stream>>>(stage, bbase, row, psrc, N);

    const int nblk64 = (N + 63) / 64;
    const int nblk16 = (N + 15) / 16;

    // layer 1
    prep_k<<<1, 256, 0, stream>>>(W1, as1, ad1, WaSD);
    alpha_k<<<nblk64, 256, 0, stream>>>(x, WaSD, asrc, adst, N);
    aggzw_k<<<nblk16, 256, 0, stream>>>(x, asrc, adst, row, psrc, W1, b1, x1, N);

    // layer 2
    prep_k<<<1, 256, 0, stream>>>(W2, as2, ad2, WaSD);
    alpha_k<<<nblk64, 256, 0, stream>>>(x1, WaSD, asrc, adst, N);
    aggzw_k<<<nblk16, 256, 0, stream>>>(x1, asrc, adst, row, psrc, W2, b2, (float*)d_out, N);
}